// Round 1
// baseline (1252.511 us; speedup 1.0000x reference)
//
#include <hip/hip_runtime.h>
#include <math.h>

#define TOKENS   8192
#define DMODEL   1024
#define HDIM     2048
#define NEXP     8
#define NSH      2
#define NGRP     10
#define R_ROUTED 16384
#define R_TOTAL  32768

typedef float  f32x4  __attribute__((ext_vector_type(4)));
typedef __bf16 bf16x8 __attribute__((ext_vector_type(8)));

typedef __attribute__((address_space(1))) const void as1_void;
typedef __attribute__((address_space(3))) void as3_void;
#define GLOAD16(g, l) __builtin_amdgcn_global_load_lds((as1_void*)(g), (as3_void*)(l), 16, 0, 0)

__device__ __forceinline__ unsigned short f2bf(float f) {
  unsigned int u = __float_as_uint(f);
  u += 0x7fffu + ((u >> 16) & 1u);
  return (unsigned short)(u >> 16);
}

// ---------------- conversion kernels ----------------

__global__ __launch_bounds__(256) void convert_x_kernel(const float* __restrict__ x,
                                                        unsigned short* __restrict__ xb) {
  int i = blockIdx.x * blockDim.x + threadIdx.x;   // over float4 groups
  const float4 v = reinterpret_cast<const float4*>(x)[i];
  ushort4 o;
  o.x = f2bf(v.x); o.y = f2bf(v.y); o.z = f2bf(v.z); o.w = f2bf(v.w);
  reinterpret_cast<ushort4*>(xb)[i] = o;
}

// transpose fp32 (R x C) -> bf16 (C x R), batched over blockIdx.z
__global__ __launch_bounds__(256) void transpose_cvt_kernel(const float* __restrict__ src,
                                                            unsigned short* __restrict__ dst,
                                                            int R, int C) {
  __shared__ float tile[32][33];
  const size_t mat = blockIdx.z;
  src += mat * (size_t)R * C;
  dst += mat * (size_t)R * C;
  const int c0 = blockIdx.x * 32, r0 = blockIdx.y * 32;
  const int tx = threadIdx.x, ty = threadIdx.y;   // block (32,8)
  #pragma unroll
  for (int j = 0; j < 4; ++j)
    tile[ty + 8 * j][tx] = src[(size_t)(r0 + ty + 8 * j) * C + c0 + tx];
  __syncthreads();
  #pragma unroll
  for (int j = 0; j < 4; ++j)
    dst[(size_t)(c0 + ty + 8 * j) * R + r0 + tx] = f2bf(tile[tx][ty + 8 * j]);
}

// ---------------- gating / routing ----------------

__global__ __launch_bounds__(64) void gate_kernel(const float* __restrict__ x,
                                                  const float* __restrict__ gw,
                                                  const float* __restrict__ gb,
                                                  int* __restrict__ topk_idx,
                                                  float* __restrict__ topk_w,
                                                  int* __restrict__ counts) {
  const int t = blockIdx.x;
  const int lane = threadIdx.x;
  const float* xr = x + (size_t)t * DMODEL;
  float acc[NEXP];
  #pragma unroll
  for (int e = 0; e < NEXP; ++e) acc[e] = 0.f;
  for (int d = lane; d < DMODEL; d += 64) {
    const float xv = xr[d];
    const float* g = gw + (size_t)d * NEXP;
    #pragma unroll
    for (int e = 0; e < NEXP; ++e) acc[e] += xv * g[e];
  }
  #pragma unroll
  for (int e = 0; e < NEXP; ++e) {
    float v = acc[e];
    v += __shfl_down(v, 32); v += __shfl_down(v, 16); v += __shfl_down(v, 8);
    v += __shfl_down(v, 4);  v += __shfl_down(v, 2);  v += __shfl_down(v, 1);
    acc[e] = v;
  }
  if (lane == 0) {
    float p[NEXP];
    float mx = -1e30f;
    #pragma unroll
    for (int e = 0; e < NEXP; ++e) { acc[e] += gb[e]; mx = fmaxf(mx, acc[e]); }
    float s = 0.f;
    #pragma unroll
    for (int e = 0; e < NEXP; ++e) { p[e] = expf(acc[e] - mx); s += p[e]; }
    const float inv = 1.f / s;
    #pragma unroll
    for (int e = 0; e < NEXP; ++e) p[e] *= inv;
    int i1 = 0; float v1 = p[0];
    #pragma unroll
    for (int e = 1; e < NEXP; ++e) if (p[e] > v1) { v1 = p[e]; i1 = e; }
    int i2 = -1; float v2 = -1e30f;
    #pragma unroll
    for (int e = 0; e < NEXP; ++e) if (e != i1 && p[e] > v2) { v2 = p[e]; i2 = e; }
    topk_idx[t * 2 + 0] = i1; topk_w[t * 2 + 0] = v1;
    topk_idx[t * 2 + 1] = i2; topk_w[t * 2 + 1] = v2;
    atomicAdd(&counts[i1], 1);
    atomicAdd(&counts[i2], 1);
  }
}

__global__ void offs_kernel(const int* __restrict__ counts, int* __restrict__ offs) {
  if (threadIdx.x == 0 && blockIdx.x == 0) {
    int cum = 0;
    for (int e = 0; e < NEXP; ++e) { offs[e] = cum; cum += counts[e]; }
    offs[8] = R_ROUTED;
    offs[9] = R_ROUTED + TOKENS;
    offs[10] = R_TOTAL;
  }
}

__global__ __launch_bounds__(256) void scatter_kernel(const int* __restrict__ topk_idx,
                                                      const float* __restrict__ topk_w,
                                                      const int* __restrict__ offs,
                                                      int* __restrict__ cursors,
                                                      int* __restrict__ row_token,
                                                      float* __restrict__ row_coef) {
  const int t = blockIdx.x * blockDim.x + threadIdx.x;
  if (t >= TOKENS) return;
  #pragma unroll
  for (int k = 0; k < 2; ++k) {
    const int e = topk_idx[t * 2 + k];
    const int pos = atomicAdd(&cursors[e], 1);
    const int r = offs[e] + pos;
    row_token[r] = t;
    row_coef[r] = topk_w[t * 2 + k];
  }
  row_token[R_ROUTED + t] = t;          row_coef[R_ROUTED + t] = 0.5f;
  row_token[R_ROUTED + TOKENS + t] = t; row_coef[R_ROUTED + TOKENS + t] = 0.5f;
}

// ---------------- grouped GEMM 1: glu = silu(X W1 + b1) * (X W2 + b2) ----------------

__global__ __launch_bounds__(256, 2) void gemm1_kernel(
    const unsigned short* __restrict__ xb,
    const unsigned short* __restrict__ w1t,
    const unsigned short* __restrict__ w2t,
    const float* __restrict__ rb1, const float* __restrict__ sb1,
    const float* __restrict__ rb2, const float* __restrict__ sb2,
    const int* __restrict__ offs,
    const int* __restrict__ row_token,
    unsigned short* __restrict__ glu) {
  const int g = blockIdx.z;
  const int off_g = offs[g];
  const int n_g = offs[g + 1] - off_g;
  const int m0 = blockIdx.x * 128;
  if (m0 >= n_g) return;
  const int n0 = blockIdx.y * 128;

  __shared__ __align__(16) unsigned short Abuf[128 * 64];
  __shared__ __align__(16) unsigned short B1buf[128 * 64];
  __shared__ __align__(16) unsigned short B2buf[128 * 64];
  __shared__ int tokL[128];

  const int tid = threadIdx.x;
  const int lane = tid & 63;
  const int wid = tid >> 6;

  if (tid < 128) {
    int r = m0 + tid;
    if (r > n_g - 1) r = n_g - 1;
    tokL[tid] = row_token[off_g + r];
  }

  const unsigned short* w1g = w1t + (size_t)g * HDIM * DMODEL;
  const unsigned short* w2g = w2t + (size_t)g * HDIM * DMODEL;

  f32x4 acc1[4][4], acc2[4][4];
  const f32x4 zero = {0.f, 0.f, 0.f, 0.f};
  #pragma unroll
  for (int i = 0; i < 4; ++i)
    #pragma unroll
    for (int j = 0; j < 4; ++j) { acc1[i][j] = zero; acc2[i][j] = zero; }

  const int wm = wid >> 1, wn = wid & 1;
  const int srow = lane >> 3;
  const int skel = (lane & 7) * 8;

  for (int k0 = 0; k0 < DMODEL; k0 += 64) {
    __syncthreads();
    #pragma unroll
    for (int cc = 0; cc < 4; ++cc) {
      const int c = wid * 4 + cc;
      const int row = c * 8 + srow;
      GLOAD16(xb + (size_t)tokL[row] * DMODEL + k0 + skel, &Abuf[c * 512]);
      GLOAD16(w1g + (size_t)(n0 + row) * DMODEL + k0 + skel, &B1buf[c * 512]);
      GLOAD16(w2g + (size_t)(n0 + row) * DMODEL + k0 + skel, &B2buf[c * 512]);
    }
    __syncthreads();
    #pragma unroll
    for (int ks = 0; ks < 2; ++ks) {
      const int kb = ks * 32 + (lane >> 4) * 8;
      bf16x8 af[4];
      #pragma unroll
      for (int mi = 0; mi < 4; ++mi) {
        const int row = wm * 64 + mi * 16 + (lane & 15);
        af[mi] = *reinterpret_cast<const bf16x8*>(&Abuf[row * 64 + kb]);
      }
      #pragma unroll
      for (int ni = 0; ni < 4; ++ni) {
        const int row = wn * 64 + ni * 16 + (lane & 15);
        const bf16x8 b1 = *reinterpret_cast<const bf16x8*>(&B1buf[row * 64 + kb]);
        const bf16x8 b2 = *reinterpret_cast<const bf16x8*>(&B2buf[row * 64 + kb]);
        #pragma unroll
        for (int mi = 0; mi < 4; ++mi) {
          acc1[mi][ni] = __builtin_amdgcn_mfma_f32_16x16x32_bf16(af[mi], b1, acc1[mi][ni], 0, 0, 0);
          acc2[mi][ni] = __builtin_amdgcn_mfma_f32_16x16x32_bf16(af[mi], b2, acc2[mi][ni], 0, 0, 0);
        }
      }
    }
  }

  const float* b1p = (g < NEXP) ? (rb1 + (size_t)g * HDIM) : (sb1 + (size_t)(g - NEXP) * HDIM);
  const float* b2p = (g < NEXP) ? (rb2 + (size_t)g * HDIM) : (sb2 + (size_t)(g - NEXP) * HDIM);

  #pragma unroll
  for (int mi = 0; mi < 4; ++mi) {
    #pragma unroll
    for (int r = 0; r < 4; ++r) {
      const int ml = wm * 64 + mi * 16 + (lane >> 4) * 4 + r;
      const int m = m0 + ml;
      if (m < n_g) {
        #pragma unroll
        for (int ni = 0; ni < 4; ++ni) {
          const int n = n0 + wn * 64 + ni * 16 + (lane & 15);
          const float p1 = acc1[mi][ni][r] + b1p[n];
          const float p2 = acc2[mi][ni][r] + b2p[n];
          const float sg = p1 / (1.0f + expf(-p1));
          glu[(size_t)(off_g + m) * HDIM + n] = f2bf(sg * p2);
        }
      }
    }
  }
}

// ---------------- grouped GEMM 2: out += coef * (glu W3 + b3) ----------------

__global__ __launch_bounds__(256, 2) void gemm2_kernel(
    const unsigned short* __restrict__ glu,
    const unsigned short* __restrict__ w3t,
    const float* __restrict__ rb3, const float* __restrict__ sb3,
    const int* __restrict__ offs,
    const int* __restrict__ row_token,
    const float* __restrict__ row_coef,
    float* __restrict__ out) {
  const int g = blockIdx.z;
  const int off_g = offs[g];
  const int n_g = offs[g + 1] - off_g;
  const int m0 = blockIdx.x * 128;
  if (m0 >= n_g) return;
  const int n0 = blockIdx.y * 128;

  __shared__ __align__(16) unsigned short Abuf[128 * 64];
  __shared__ __align__(16) unsigned short Bbuf[128 * 64];
  __shared__ int tokL[128];
  __shared__ float coefL[128];

  const int tid = threadIdx.x;
  const int lane = tid & 63;
  const int wid = tid >> 6;

  if (tid < 128) {
    int r = m0 + tid;
    if (r > n_g - 1) r = n_g - 1;
    tokL[tid] = row_token[off_g + r];
    coefL[tid] = row_coef[off_g + r];
  }

  const unsigned short* w3g = w3t + (size_t)g * DMODEL * HDIM;

  f32x4 acc[4][4];
  const f32x4 zero = {0.f, 0.f, 0.f, 0.f};
  #pragma unroll
  for (int i = 0; i < 4; ++i)
    #pragma unroll
    for (int j = 0; j < 4; ++j) acc[i][j] = zero;

  const int wm = wid >> 1, wn = wid & 1;
  const int srow = lane >> 3;
  const int skel = (lane & 7) * 8;

  for (int k0 = 0; k0 < HDIM; k0 += 64) {
    __syncthreads();
    #pragma unroll
    for (int cc = 0; cc < 4; ++cc) {
      const int c = wid * 4 + cc;
      const int row = c * 8 + srow;
      int ar = m0 + row;
      if (ar > n_g - 1) ar = n_g - 1;
      GLOAD16(glu + (size_t)(off_g + ar) * HDIM + k0 + skel, &Abuf[c * 512]);
      GLOAD16(w3g + (size_t)(n0 + row) * HDIM + k0 + skel, &Bbuf[c * 512]);
    }
    __syncthreads();
    #pragma unroll
    for (int ks = 0; ks < 2; ++ks) {
      const int kb = ks * 32 + (lane >> 4) * 8;
      bf16x8 af[4];
      #pragma unroll
      for (int mi = 0; mi < 4; ++mi) {
        const int row = wm * 64 + mi * 16 + (lane & 15);
        af[mi] = *reinterpret_cast<const bf16x8*>(&Abuf[row * 64 + kb]);
      }
      #pragma unroll
      for (int ni = 0; ni < 4; ++ni) {
        const int row = wn * 64 + ni * 16 + (lane & 15);
        const bf16x8 b = *reinterpret_cast<const bf16x8*>(&Bbuf[row * 64 + kb]);
        #pragma unroll
        for (int mi = 0; mi < 4; ++mi)
          acc[mi][ni] = __builtin_amdgcn_mfma_f32_16x16x32_bf16(af[mi], b, acc[mi][ni], 0, 0, 0);
      }
    }
  }

  const float* b3p = (g < NEXP) ? (rb3 + (size_t)g * DMODEL) : (sb3 + (size_t)(g - NEXP) * DMODEL);

  #pragma unroll
  for (int mi = 0; mi < 4; ++mi) {
    #pragma unroll
    for (int r = 0; r < 4; ++r) {
      const int ml = wm * 64 + mi * 16 + (lane >> 4) * 4 + r;
      const int m = m0 + ml;
      if (m < n_g) {
        const float cf = coefL[ml];
        float* orow = out + (size_t)tokL[ml] * DMODEL;
        #pragma unroll
        for (int ni = 0; ni < 4; ++ni) {
          const int n = n0 + wn * 64 + ni * 16 + (lane & 15);
          atomicAdd(&orow[n], (acc[mi][ni][r] + b3p[n]) * cf);
        }
      }
    }
  }
}

// ---------------- launch ----------------

extern "C" void kernel_launch(void* const* d_in, const int* in_sizes, int n_in,
                              void* d_out, int out_size, void* d_ws, size_t ws_size,
                              hipStream_t stream) {
  const float* x      = (const float*)d_in[0];
  const float* gate_w = (const float*)d_in[1];
  const float* gate_b = (const float*)d_in[2];
  const float* rw1    = (const float*)d_in[3];
  const float* rb1    = (const float*)d_in[4];
  const float* rw2    = (const float*)d_in[5];
  const float* rb2    = (const float*)d_in[6];
  const float* rw3    = (const float*)d_in[7];
  const float* rb3    = (const float*)d_in[8];
  const float* sw1    = (const float*)d_in[9];
  const float* sb1    = (const float*)d_in[10];
  const float* sw2    = (const float*)d_in[11];
  const float* sb2    = (const float*)d_in[12];
  const float* sw3    = (const float*)d_in[13];
  const float* sb3    = (const float*)d_in[14];
  float* out = (float*)d_out;

  // workspace layout
  const size_t XB_OFF   = 0;
  const size_t W1T_OFF  = XB_OFF  + (size_t)TOKENS * DMODEL * 2;
  const size_t W2T_OFF  = W1T_OFF + (size_t)NGRP * HDIM * DMODEL * 2;
  const size_t W3T_OFF  = W2T_OFF + (size_t)NGRP * HDIM * DMODEL * 2;
  const size_t GLU_OFF  = W3T_OFF + (size_t)NGRP * DMODEL * HDIM * 2;
  const size_t RTOK_OFF = GLU_OFF + (size_t)R_TOTAL * HDIM * 2;
  const size_t RCOE_OFF = RTOK_OFF + (size_t)R_TOTAL * 4;
  const size_t TKI_OFF  = RCOE_OFF + (size_t)R_TOTAL * 4;
  const size_t TKW_OFF  = TKI_OFF + (size_t)TOKENS * 2 * 4;
  const size_t META_OFF = TKW_OFF + (size_t)TOKENS * 2 * 4;
  const size_t NEED     = META_OFF + 256;
  if (ws_size < NEED) return;  // workspace too small; fail loudly via wrong output

  char* ws = (char*)d_ws;
  unsigned short* xb   = (unsigned short*)(ws + XB_OFF);
  unsigned short* w1t  = (unsigned short*)(ws + W1T_OFF);
  unsigned short* w2t  = (unsigned short*)(ws + W2T_OFF);
  unsigned short* w3t  = (unsigned short*)(ws + W3T_OFF);
  unsigned short* glu  = (unsigned short*)(ws + GLU_OFF);
  int*   row_token = (int*)(ws + RTOK_OFF);
  float* row_coef  = (float*)(ws + RCOE_OFF);
  int*   topk_idx  = (int*)(ws + TKI_OFF);
  float* topk_w    = (float*)(ws + TKW_OFF);
  int*   counts    = (int*)(ws + META_OFF);
  int*   offs      = counts + 16;
  int*   cursors   = counts + 32;

  hipMemsetAsync(counts, 0, 192, stream);
  hipMemsetAsync(out, 0, (size_t)TOKENS * DMODEL * sizeof(float), stream);

  convert_x_kernel<<<TOKENS * DMODEL / 4 / 256, 256, 0, stream>>>(x, xb);

  dim3 tb(32, 8);
  transpose_cvt_kernel<<<dim3(HDIM / 32, DMODEL / 32, NEXP), tb, 0, stream>>>(rw1, w1t, DMODEL, HDIM);
  transpose_cvt_kernel<<<dim3(HDIM / 32, DMODEL / 32, NSH), tb, 0, stream>>>(
      sw1, w1t + (size_t)NEXP * HDIM * DMODEL, DMODEL, HDIM);
  transpose_cvt_kernel<<<dim3(HDIM / 32, DMODEL / 32, NEXP), tb, 0, stream>>>(rw2, w2t, DMODEL, HDIM);
  transpose_cvt_kernel<<<dim3(HDIM / 32, DMODEL / 32, NSH), tb, 0, stream>>>(
      sw2, w2t + (size_t)NEXP * HDIM * DMODEL, DMODEL, HDIM);
  transpose_cvt_kernel<<<dim3(DMODEL / 32, HDIM / 32, NEXP), tb, 0, stream>>>(rw3, w3t, HDIM, DMODEL);
  transpose_cvt_kernel<<<dim3(DMODEL / 32, HDIM / 32, NSH), tb, 0, stream>>>(
      sw3, w3t + (size_t)NEXP * DMODEL * HDIM, HDIM, DMODEL);

  gate_kernel<<<TOKENS, 64, 0, stream>>>(x, gate_w, gate_b, topk_idx, topk_w, counts);
  offs_kernel<<<1, 64, 0, stream>>>(counts, offs);
  scatter_kernel<<<TOKENS / 256, 256, 0, stream>>>(topk_idx, topk_w, offs, cursors,
                                                   row_token, row_coef);

  gemm1_kernel<<<dim3(64, HDIM / 128, NGRP), 256, 0, stream>>>(
      xb, w1t, w2t, rb1, sb1, rb2, sb2, offs, row_token, glu);
  gemm2_kernel<<<dim3(64, DMODEL / 128, NGRP), 256, 0, stream>>>(
      glu, w3t, rb3, sb3, offs, row_token, row_coef, out);
}

// Round 2
// 1154.436 us; speedup vs baseline: 1.0850x; 1.0850x over previous
//
#include <hip/hip_runtime.h>
#include <math.h>

#define TOKENS   8192
#define DMODEL   1024
#define HDIM     2048
#define NEXP     8
#define NSH      2
#define NGRP     10
#define R_ROUTED 16384
#define R_TOTAL  32768

typedef float  f32x4  __attribute__((ext_vector_type(4)));
typedef __bf16 bf16x8 __attribute__((ext_vector_type(8)));

typedef __attribute__((address_space(1))) const void as1_void;
typedef __attribute__((address_space(3))) void as3_void;
#define GLOAD16(g, l) __builtin_amdgcn_global_load_lds((as1_void*)(g), (as3_void*)(l), 16, 0, 0)

__device__ __forceinline__ unsigned short f2bf(float f) {
  unsigned int u = __float_as_uint(f);
  u += 0x7fffu + ((u >> 16) & 1u);
  return (unsigned short)(u >> 16);
}

// ---------------- conversion kernels ----------------

__global__ __launch_bounds__(256) void convert_x_kernel(const float* __restrict__ x,
                                                        unsigned short* __restrict__ xb) {
  int i = blockIdx.x * blockDim.x + threadIdx.x;   // over float4 groups
  const float4 v = reinterpret_cast<const float4*>(x)[i];
  ushort4 o;
  o.x = f2bf(v.x); o.y = f2bf(v.y); o.z = f2bf(v.z); o.w = f2bf(v.w);
  reinterpret_cast<ushort4*>(xb)[i] = o;
}

// transpose fp32 (R x C) -> bf16 (C x R), batched over blockIdx.z
__global__ __launch_bounds__(256) void transpose_cvt_kernel(const float* __restrict__ src,
                                                            unsigned short* __restrict__ dst,
                                                            int R, int C) {
  __shared__ float tile[32][33];
  const size_t mat = blockIdx.z;
  src += mat * (size_t)R * C;
  dst += mat * (size_t)R * C;
  const int c0 = blockIdx.x * 32, r0 = blockIdx.y * 32;
  const int tx = threadIdx.x, ty = threadIdx.y;   // block (32,8)
  #pragma unroll
  for (int j = 0; j < 4; ++j)
    tile[ty + 8 * j][tx] = src[(size_t)(r0 + ty + 8 * j) * C + c0 + tx];
  __syncthreads();
  #pragma unroll
  for (int j = 0; j < 4; ++j)
    dst[(size_t)(c0 + ty + 8 * j) * R + r0 + tx] = f2bf(tile[tx][ty + 8 * j]);
}

// ---------------- gating / routing ----------------

__global__ __launch_bounds__(64) void gate_kernel(const float* __restrict__ x,
                                                  const float* __restrict__ gw,
                                                  const float* __restrict__ gb,
                                                  int* __restrict__ topk_idx,
                                                  float* __restrict__ topk_w,
                                                  int* __restrict__ counts) {
  const int t = blockIdx.x;
  const int lane = threadIdx.x;
  const float* xr = x + (size_t)t * DMODEL;
  float acc[NEXP];
  #pragma unroll
  for (int e = 0; e < NEXP; ++e) acc[e] = 0.f;
  for (int d = lane; d < DMODEL; d += 64) {
    const float xv = xr[d];
    const float* g = gw + (size_t)d * NEXP;
    #pragma unroll
    for (int e = 0; e < NEXP; ++e) acc[e] += xv * g[e];
  }
  #pragma unroll
  for (int e = 0; e < NEXP; ++e) {
    float v = acc[e];
    v += __shfl_down(v, 32); v += __shfl_down(v, 16); v += __shfl_down(v, 8);
    v += __shfl_down(v, 4);  v += __shfl_down(v, 2);  v += __shfl_down(v, 1);
    acc[e] = v;
  }
  if (lane == 0) {
    float p[NEXP];
    float mx = -1e30f;
    #pragma unroll
    for (int e = 0; e < NEXP; ++e) { acc[e] += gb[e]; mx = fmaxf(mx, acc[e]); }
    float s = 0.f;
    #pragma unroll
    for (int e = 0; e < NEXP; ++e) { p[e] = expf(acc[e] - mx); s += p[e]; }
    const float inv = 1.f / s;
    #pragma unroll
    for (int e = 0; e < NEXP; ++e) p[e] *= inv;
    int i1 = 0; float v1 = p[0];
    #pragma unroll
    for (int e = 1; e < NEXP; ++e) if (p[e] > v1) { v1 = p[e]; i1 = e; }
    int i2 = -1; float v2 = -1e30f;
    #pragma unroll
    for (int e = 0; e < NEXP; ++e) if (e != i1 && p[e] > v2) { v2 = p[e]; i2 = e; }
    topk_idx[t * 2 + 0] = i1; topk_w[t * 2 + 0] = v1;
    topk_idx[t * 2 + 1] = i2; topk_w[t * 2 + 1] = v2;
    atomicAdd(&counts[i1], 1);
    atomicAdd(&counts[i2], 1);
  }
}

__global__ void offs_kernel(const int* __restrict__ counts, int* __restrict__ offs) {
  if (threadIdx.x == 0 && blockIdx.x == 0) {
    int cum = 0;
    for (int e = 0; e < NEXP; ++e) { offs[e] = cum; cum += counts[e]; }
    offs[8] = R_ROUTED;
    offs[9] = R_ROUTED + TOKENS;
    offs[10] = R_TOTAL;
  }
}

__global__ __launch_bounds__(256) void scatter_kernel(const int* __restrict__ topk_idx,
                                                      const float* __restrict__ topk_w,
                                                      const int* __restrict__ offs,
                                                      int* __restrict__ cursors,
                                                      int* __restrict__ row_token,
                                                      float* __restrict__ row_coef) {
  const int t = blockIdx.x * blockDim.x + threadIdx.x;
  if (t >= TOKENS) return;
  #pragma unroll
  for (int k = 0; k < 2; ++k) {
    const int e = topk_idx[t * 2 + k];
    const int pos = atomicAdd(&cursors[e], 1);
    const int r = offs[e] + pos;
    row_token[r] = t;
    row_coef[r] = topk_w[t * 2 + k];
  }
  row_token[R_ROUTED + t] = t;          row_coef[R_ROUTED + t] = 0.5f;
  row_token[R_ROUTED + TOKENS + t] = t; row_coef[R_ROUTED + TOKENS + t] = 0.5f;
}

// ---------------- grouped GEMM 1: glu = silu(X W1 + b1) * (X W2 + b2) ----------------
// LDS layout [128 rows][8 chunks of 16B]; slot (row, j) holds global k-chunk j ^ (row&7)
// (written via pre-swizzled global source, read via XORed ds_read address).

__global__ __launch_bounds__(256, 2) void gemm1_kernel(
    const unsigned short* __restrict__ xb,
    const unsigned short* __restrict__ w1t,
    const unsigned short* __restrict__ w2t,
    const float* __restrict__ rb1, const float* __restrict__ sb1,
    const float* __restrict__ rb2, const float* __restrict__ sb2,
    const int* __restrict__ offs,
    const int* __restrict__ row_token,
    unsigned short* __restrict__ glu) {
  const int g = blockIdx.z;
  const int off_g = offs[g];
  const int n_g = offs[g + 1] - off_g;
  const int m0 = blockIdx.x * 128;
  if (m0 >= n_g) return;
  const int n0 = blockIdx.y * 128;

  __shared__ __align__(16) unsigned short Abuf[128 * 64];
  __shared__ __align__(16) unsigned short B1buf[128 * 64];
  __shared__ __align__(16) unsigned short B2buf[128 * 64];
  __shared__ int tokL[128];

  const int tid = threadIdx.x;
  const int lane = tid & 63;
  const int wid = tid >> 6;

  if (tid < 128) {
    int r = m0 + tid;
    if (r > n_g - 1) r = n_g - 1;
    tokL[tid] = row_token[off_g + r];
  }

  const unsigned short* w1g = w1t + (size_t)g * HDIM * DMODEL;
  const unsigned short* w2g = w2t + (size_t)g * HDIM * DMODEL;

  f32x4 acc1[4][4], acc2[4][4];
  const f32x4 zero = {0.f, 0.f, 0.f, 0.f};
  #pragma unroll
  for (int i = 0; i < 4; ++i)
    #pragma unroll
    for (int j = 0; j < 4; ++j) { acc1[i][j] = zero; acc2[i][j] = zero; }

  const int wm = wid >> 1, wn = wid & 1;
  const int srow = lane >> 3;                               // staging sub-row 0..7
  const int ssrc = ((lane & 7) ^ (lane >> 3)) * 8;          // pre-swizzled source chunk (elems)
  const int kq   = lane >> 4;                               // 0..3
  const int xorb = lane & 7;                                // read-side XOR band

  for (int k0 = 0; k0 < DMODEL; k0 += 64) {
    __syncthreads();
    #pragma unroll
    for (int cc = 0; cc < 4; ++cc) {
      const int c = wid * 4 + cc;
      const int row = c * 8 + srow;
      GLOAD16(xb + (size_t)tokL[row] * DMODEL + k0 + ssrc, &Abuf[c * 512]);
      GLOAD16(w1g + (size_t)(n0 + row) * DMODEL + k0 + ssrc, &B1buf[c * 512]);
      GLOAD16(w2g + (size_t)(n0 + row) * DMODEL + k0 + ssrc, &B2buf[c * 512]);
    }
    __syncthreads();
    #pragma unroll
    for (int ks = 0; ks < 2; ++ks) {
      const int kc = ks * 4 + kq;                           // global k-chunk 0..7
      const int koff = (kc ^ xorb) * 8;                     // swizzled LDS chunk (elems)
      bf16x8 af[4];
      #pragma unroll
      for (int mi = 0; mi < 4; ++mi) {
        const int row = wm * 64 + mi * 16 + (lane & 15);
        af[mi] = *reinterpret_cast<const bf16x8*>(&Abuf[row * 64 + koff]);
      }
      #pragma unroll
      for (int ni = 0; ni < 4; ++ni) {
        const int row = wn * 64 + ni * 16 + (lane & 15);
        const bf16x8 b1 = *reinterpret_cast<const bf16x8*>(&B1buf[row * 64 + koff]);
        const bf16x8 b2 = *reinterpret_cast<const bf16x8*>(&B2buf[row * 64 + koff]);
        #pragma unroll
        for (int mi = 0; mi < 4; ++mi) {
          acc1[mi][ni] = __builtin_amdgcn_mfma_f32_16x16x32_bf16(af[mi], b1, acc1[mi][ni], 0, 0, 0);
          acc2[mi][ni] = __builtin_amdgcn_mfma_f32_16x16x32_bf16(af[mi], b2, acc2[mi][ni], 0, 0, 0);
        }
      }
    }
  }

  const float* b1p = (g < NEXP) ? (rb1 + (size_t)g * HDIM) : (sb1 + (size_t)(g - NEXP) * HDIM);
  const float* b2p = (g < NEXP) ? (rb2 + (size_t)g * HDIM) : (sb2 + (size_t)(g - NEXP) * HDIM);

  #pragma unroll
  for (int mi = 0; mi < 4; ++mi) {
    #pragma unroll
    for (int r = 0; r < 4; ++r) {
      const int ml = wm * 64 + mi * 16 + (lane >> 4) * 4 + r;
      const int m = m0 + ml;
      if (m < n_g) {
        #pragma unroll
        for (int ni = 0; ni < 4; ++ni) {
          const int n = n0 + wn * 64 + ni * 16 + (lane & 15);
          const float p1 = acc1[mi][ni][r] + b1p[n];
          const float p2 = acc2[mi][ni][r] + b2p[n];
          const float sg = p1 / (1.0f + expf(-p1));
          glu[(size_t)(off_g + m) * HDIM + n] = f2bf(sg * p2);
        }
      }
    }
  }
}

// ---------------- grouped GEMM 2: out += coef * (glu W3 + b3) ----------------

__global__ __launch_bounds__(256, 2) void gemm2_kernel(
    const unsigned short* __restrict__ glu,
    const unsigned short* __restrict__ w3t,
    const float* __restrict__ rb3, const float* __restrict__ sb3,
    const int* __restrict__ offs,
    const int* __restrict__ row_token,
    const float* __restrict__ row_coef,
    float* __restrict__ out) {
  const int g = blockIdx.z;
  const int off_g = offs[g];
  const int n_g = offs[g + 1] - off_g;
  const int m0 = blockIdx.x * 128;
  if (m0 >= n_g) return;
  const int n0 = blockIdx.y * 128;

  __shared__ __align__(16) unsigned short Abuf[128 * 64];
  __shared__ __align__(16) unsigned short Bbuf[128 * 64];
  __shared__ int tokL[128];
  __shared__ float coefL[128];

  const int tid = threadIdx.x;
  const int lane = tid & 63;
  const int wid = tid >> 6;

  if (tid < 128) {
    int r = m0 + tid;
    if (r > n_g - 1) r = n_g - 1;
    tokL[tid] = row_token[off_g + r];
    coefL[tid] = row_coef[off_g + r];
  }

  const unsigned short* w3g = w3t + (size_t)g * DMODEL * HDIM;

  f32x4 acc[4][4];
  const f32x4 zero = {0.f, 0.f, 0.f, 0.f};
  #pragma unroll
  for (int i = 0; i < 4; ++i)
    #pragma unroll
    for (int j = 0; j < 4; ++j) acc[i][j] = zero;

  const int wm = wid >> 1, wn = wid & 1;
  const int srow = lane >> 3;
  const int ssrc = ((lane & 7) ^ (lane >> 3)) * 8;
  const int kq   = lane >> 4;
  const int xorb = lane & 7;

  for (int k0 = 0; k0 < HDIM; k0 += 64) {
    __syncthreads();
    #pragma unroll
    for (int cc = 0; cc < 4; ++cc) {
      const int c = wid * 4 + cc;
      const int row = c * 8 + srow;
      int ar = m0 + row;
      if (ar > n_g - 1) ar = n_g - 1;
      GLOAD16(glu + (size_t)(off_g + ar) * HDIM + k0 + ssrc, &Abuf[c * 512]);
      GLOAD16(w3g + (size_t)(n0 + row) * HDIM + k0 + ssrc, &Bbuf[c * 512]);
    }
    __syncthreads();
    #pragma unroll
    for (int ks = 0; ks < 2; ++ks) {
      const int kc = ks * 4 + kq;
      const int koff = (kc ^ xorb) * 8;
      bf16x8 af[4];
      #pragma unroll
      for (int mi = 0; mi < 4; ++mi) {
        const int row = wm * 64 + mi * 16 + (lane & 15);
        af[mi] = *reinterpret_cast<const bf16x8*>(&Abuf[row * 64 + koff]);
      }
      #pragma unroll
      for (int ni = 0; ni < 4; ++ni) {
        const int row = wn * 64 + ni * 16 + (lane & 15);
        const bf16x8 b = *reinterpret_cast<const bf16x8*>(&Bbuf[row * 64 + koff]);
        #pragma unroll
        for (int mi = 0; mi < 4; ++mi)
          acc[mi][ni] = __builtin_amdgcn_mfma_f32_16x16x32_bf16(af[mi], b, acc[mi][ni], 0, 0, 0);
      }
    }
  }

  const float* b3p = (g < NEXP) ? (rb3 + (size_t)g * DMODEL) : (sb3 + (size_t)(g - NEXP) * DMODEL);

  #pragma unroll
  for (int mi = 0; mi < 4; ++mi) {
    #pragma unroll
    for (int r = 0; r < 4; ++r) {
      const int ml = wm * 64 + mi * 16 + (lane >> 4) * 4 + r;
      const int m = m0 + ml;
      if (m < n_g) {
        const float cf = coefL[ml];
        float* orow = out + (size_t)tokL[ml] * DMODEL;
        #pragma unroll
        for (int ni = 0; ni < 4; ++ni) {
          const int n = n0 + wn * 64 + ni * 16 + (lane & 15);
          atomicAdd(&orow[n], (acc[mi][ni][r] + b3p[n]) * cf);
        }
      }
    }
  }
}

// ---------------- launch ----------------

extern "C" void kernel_launch(void* const* d_in, const int* in_sizes, int n_in,
                              void* d_out, int out_size, void* d_ws, size_t ws_size,
                              hipStream_t stream) {
  const float* x      = (const float*)d_in[0];
  const float* gate_w = (const float*)d_in[1];
  const float* gate_b = (const float*)d_in[2];
  const float* rw1    = (const float*)d_in[3];
  const float* rb1    = (const float*)d_in[4];
  const float* rw2    = (const float*)d_in[5];
  const float* rb2    = (const float*)d_in[6];
  const float* rw3    = (const float*)d_in[7];
  const float* rb3    = (const float*)d_in[8];
  const float* sw1    = (const float*)d_in[9];
  const float* sb1    = (const float*)d_in[10];
  const float* sw2    = (const float*)d_in[11];
  const float* sb2    = (const float*)d_in[12];
  const float* sw3    = (const float*)d_in[13];
  const float* sb3    = (const float*)d_in[14];
  float* out = (float*)d_out;

  // workspace layout
  const size_t XB_OFF   = 0;
  const size_t W1T_OFF  = XB_OFF  + (size_t)TOKENS * DMODEL * 2;
  const size_t W2T_OFF  = W1T_OFF + (size_t)NGRP * HDIM * DMODEL * 2;
  const size_t W3T_OFF  = W2T_OFF + (size_t)NGRP * HDIM * DMODEL * 2;
  const size_t GLU_OFF  = W3T_OFF + (size_t)NGRP * DMODEL * HDIM * 2;
  const size_t RTOK_OFF = GLU_OFF + (size_t)R_TOTAL * HDIM * 2;
  const size_t RCOE_OFF = RTOK_OFF + (size_t)R_TOTAL * 4;
  const size_t TKI_OFF  = RCOE_OFF + (size_t)R_TOTAL * 4;
  const size_t TKW_OFF  = TKI_OFF + (size_t)TOKENS * 2 * 4;
  const size_t META_OFF = TKW_OFF + (size_t)TOKENS * 2 * 4;
  const size_t NEED     = META_OFF + 256;
  if (ws_size < NEED) return;

  char* ws = (char*)d_ws;
  unsigned short* xb   = (unsigned short*)(ws + XB_OFF);
  unsigned short* w1t  = (unsigned short*)(ws + W1T_OFF);
  unsigned short* w2t  = (unsigned short*)(ws + W2T_OFF);
  unsigned short* w3t  = (unsigned short*)(ws + W3T_OFF);
  unsigned short* glu  = (unsigned short*)(ws + GLU_OFF);
  int*   row_token = (int*)(ws + RTOK_OFF);
  float* row_coef  = (float*)(ws + RCOE_OFF);
  int*   topk_idx  = (int*)(ws + TKI_OFF);
  float* topk_w    = (float*)(ws + TKW_OFF);
  int*   counts    = (int*)(ws + META_OFF);
  int*   offs      = counts + 16;
  int*   cursors   = counts + 32;

  hipMemsetAsync(counts, 0, 192, stream);
  hipMemsetAsync(out, 0, (size_t)TOKENS * DMODEL * sizeof(float), stream);

  convert_x_kernel<<<TOKENS * DMODEL / 4 / 256, 256, 0, stream>>>(x, xb);

  dim3 tb(32, 8);
  transpose_cvt_kernel<<<dim3(HDIM / 32, DMODEL / 32, NEXP), tb, 0, stream>>>(rw1, w1t, DMODEL, HDIM);
  transpose_cvt_kernel<<<dim3(HDIM / 32, DMODEL / 32, NSH), tb, 0, stream>>>(
      sw1, w1t + (size_t)NEXP * HDIM * DMODEL, DMODEL, HDIM);
  transpose_cvt_kernel<<<dim3(HDIM / 32, DMODEL / 32, NEXP), tb, 0, stream>>>(rw2, w2t, DMODEL, HDIM);
  transpose_cvt_kernel<<<dim3(HDIM / 32, DMODEL / 32, NSH), tb, 0, stream>>>(
      sw2, w2t + (size_t)NEXP * HDIM * DMODEL, DMODEL, HDIM);
  transpose_cvt_kernel<<<dim3(DMODEL / 32, HDIM / 32, NEXP), tb, 0, stream>>>(rw3, w3t, HDIM, DMODEL);
  transpose_cvt_kernel<<<dim3(DMODEL / 32, HDIM / 32, NSH), tb, 0, stream>>>(
      sw3, w3t + (size_t)NEXP * DMODEL * HDIM, HDIM, DMODEL);

  gate_kernel<<<TOKENS, 64, 0, stream>>>(x, gate_w, gate_b, topk_idx, topk_w, counts);
  offs_kernel<<<1, 64, 0, stream>>>(counts, offs);
  scatter_kernel<<<TOKENS / 256, 256, 0, stream>>>(topk_idx, topk_w, offs, cursors,
                                                   row_token, row_coef);

  gemm1_kernel<<<dim3(64, HDIM / 128, NGRP), 256, 0, stream>>>(
      xb, w1t, w2t, rb1, sb1, rb2, sb2, offs, row_token, glu);
  gemm2_kernel<<<dim3(64, DMODEL / 128, NGRP), 256, 0, stream>>>(
      glu, w3t, rb3, sb3, offs, row_token, row_coef, out);
}